// Round 6
// baseline (277.426 us; speedup 1.0000x reference)
//
#include <hip/hip_runtime.h>
#include <math.h>

#define Bn 128
#define Cn 64
#define Tn 500

typedef float v2f __attribute__((ext_vector_type(2)));

__device__ __forceinline__ v2f elu2(v2f v) {
  // elu(v) = exp(min(v,0)) - 1 + max(v,0)   (branch/select-free, packable)
  v2f z; z.x = 0.f; z.y = 0.f;
  v2f mn = __builtin_elementwise_min(v, z);
  v2f mx = __builtin_elementwise_max(v, z);
  v2f e; e.x = __expf(mn.x); e.y = __expf(mn.y);
  return e - 1.f + mx;
}

// ---------------------------------------------------------------------------
// Stage 1: EEG feature extractor — R0 structure (best measured ~141 µs at
// nominal clocks; sessions vary ±10%). Register/packing attacks falsified
// (R12 spill disaster, R13 -3%). Near its realistic floor — leave alone.
__global__ __launch_bounds__(256) void feat_kernel(
    const float* __restrict__ x, const float* __restrict__ w_conv1,
    const float* __restrict__ bn1, const float* __restrict__ w_dw,
    const float* __restrict__ bn2, const float* __restrict__ w_sdw,
    const float* __restrict__ w_spw, const float* __restrict__ bn3,
    float* __restrict__ feats, float* __restrict__ gzero)
{
  __shared__ float xs[544];
  __shared__ v2f   wL[200];
  __shared__ v2f   s1p[8 * 522];
  __shared__ float red[64];
  const int n = blockIdx.x;
  const int tid = threadIdx.x;
  const int op = tid & 7;
  const int tg = tid >> 3;
  const int T0 = tg * 16;

  if (n == 0 && tid < 64) gzero[tid] = 0.f;   // zero gsum1|gsum2

  if (tid < 125) *(float4*)&xs[16 + 4 * tid] = ((const float4*)(x + n * Tn))[tid];
  if (tid < 16) xs[tid] = 0.f;
  else if (tid < 44) xs[500 + tid] = 0.f;
  if (tid < 200) {
    int kk = tid % 25, opp = tid / 25;
    v2f w; w.x = w_conv1[opp * 50 + kk]; w.y = w_conv1[opp * 50 + 25 + kk];
    wL[opp * 25 + kk] = w;
  }

  v2f sc1, sh1, sc2, sh2, sc3, sh3;
  {
    int c0 = 2 * op, c1 = 2 * op + 1;
    sc1.x = bn1[c0] * rsqrtf(bn1[48 + c0] + 1e-5f);
    sc1.y = bn1[c1] * rsqrtf(bn1[48 + c1] + 1e-5f);
    sh1.x = bn1[16 + c0] - bn1[32 + c0] * sc1.x;
    sh1.y = bn1[16 + c1] - bn1[32 + c1] * sc1.y;
    sc2.x = bn2[c0] * rsqrtf(bn2[48 + c0] + 1e-5f);
    sc2.y = bn2[c1] * rsqrtf(bn2[48 + c1] + 1e-5f);
    sh2.x = bn2[16 + c0] - bn2[32 + c0] * sc2.x;
    sh2.y = bn2[16 + c1] - bn2[32 + c1] * sc2.y;
  }
  v2f wd[3], we[3];
#pragma unroll
  for (int k = 0; k < 3; ++k) {
    wd[k].x = w_dw[6 * op + k];     wd[k].y = w_dw[6 * op + 3 + k];
    we[k].x = w_sdw[6 * op + k];    we[k].y = w_sdw[6 * op + 3 + k];
  }
  __syncthreads();

  float xw[48];
#pragma unroll
  for (int i = 0; i < 12; ++i) *(float4*)&xw[4 * i] = *(const float4*)&xs[T0 + 4 * i];
  v2f ce[20];
#pragma unroll
  for (int j = 0; j < 20; ++j) { ce[j].x = 0.f; ce[j].y = 0.f; }
#pragma unroll
  for (int k = 0; k < 25; ++k) {
    v2f wt = wL[op * 25 + k];
#pragma unroll
    for (int j = 0; j < 20; ++j) ce[j] += wt * xw[j + k + 2];
  }
  v2f zero; zero.x = 0.f; zero.y = 0.f;
#pragma unroll
  for (int j = 0; j < 20; ++j) {
    int t = T0 - 2 + j;
    v2f v = elu2(ce[j] * sc1 + sh1);
    ce[j] = ((unsigned)t < (unsigned)Tn) ? v : zero;
  }

  v2f d[18];
#pragma unroll
  for (int j = 0; j < 18; ++j) {
    int t = T0 - 1 + j;
    v2f a = ce[j] * wd[0] + ce[j + 1] * wd[1] + ce[j + 2] * wd[2];
    v2f v = elu2(a * sc2 + sh2);
    d[j] = ((unsigned)t < (unsigned)Tn) ? v : zero;
  }

#pragma unroll
  for (int r = 0; r < 8; ++r) {
    v2f s0 = d[2 * r] * we[0] + d[2 * r + 1] * we[1] + d[2 * r + 2] * we[2];
    v2f s1 = d[2 * r + 1] * we[0] + d[2 * r + 2] * we[1] + d[2 * r + 3] * we[2];
    float4 st; st.x = s0.x; st.y = s0.y; st.z = s1.x; st.w = s1.y;
    *(float4*)&s1p[op * 522 + T0 + 2 * r] = st;
  }

  const int oq = tid & 3, tgp = tid >> 2;
  v2f wA[16], wB[16];
#pragma unroll
  for (int q = 0; q < 16; ++q) {
    wA[q].x = w_spw[(4 * oq) * 16 + q];     wA[q].y = w_spw[(4 * oq + 1) * 16 + q];
    wB[q].x = w_spw[(4 * oq + 2) * 16 + q]; wB[q].y = w_spw[(4 * oq + 3) * 16 + q];
  }
  {
    int c0 = 4 * oq;
    sc3.x = bn3[c0] * rsqrtf(bn3[48 + c0] + 1e-5f);
    sc3.y = bn3[c0 + 1] * rsqrtf(bn3[48 + c0 + 1] + 1e-5f);
    sh3.x = bn3[16 + c0] - bn3[32 + c0] * sc3.x;
    sh3.y = bn3[16 + c0 + 1] - bn3[32 + c0 + 1] * sc3.y;
  }
  v2f sc3b, sh3b;
  {
    int c0 = 4 * oq + 2;
    sc3b.x = bn3[c0] * rsqrtf(bn3[48 + c0] + 1e-5f);
    sc3b.y = bn3[c0 + 1] * rsqrtf(bn3[48 + c0 + 1] + 1e-5f);
    sh3b.x = bn3[16 + c0] - bn3[32 + c0] * sc3b.x;
    sh3b.y = bn3[16 + c0 + 1] - bn3[32 + c0 + 1] * sc3b.y;
  }
  v2f tsA = zero, tsB = zero;
  __syncthreads();
#pragma unroll
  for (int tt = 0; tt < 8; ++tt) {
    int t = tgp + 64 * tt;
    if (tt < 7 || tgp < Tn - 448) {
      v2f aA = zero, aB = zero;
#pragma unroll
      for (int opr = 0; opr < 8; ++opr) {
        v2f inq = s1p[opr * 522 + t];
        aA += wA[2 * opr] * inq.x;  aA += wA[2 * opr + 1] * inq.y;
        aB += wB[2 * opr] * inq.x;  aB += wB[2 * opr + 1] * inq.y;
      }
      tsA += elu2(aA * sc3 + sh3);
      tsB += elu2(aB * sc3b + sh3b);
    }
  }
#pragma unroll
  for (int dd = 4; dd <= 32; dd <<= 1) {
    tsA.x += __shfl_xor(tsA.x, dd, 64); tsA.y += __shfl_xor(tsA.y, dd, 64);
    tsB.x += __shfl_xor(tsB.x, dd, 64); tsB.y += __shfl_xor(tsB.y, dd, 64);
  }
  if ((tid & 63) < 4) {
    float4 st; st.x = tsA.x; st.y = tsA.y; st.z = tsB.x; st.w = tsB.y;
    *(float4*)&red[(tid >> 6) * 16 + oq * 4] = st;
  }
  __syncthreads();
  if (tid < 16)
    feats[n * 16 + tid] =
        (red[tid] + red[16 + tid] + red[32 + tid] + red[48 + tid]) * (1.f / 500.f);
}

// ---------------------------------------------------------------------------
// R16: batch-independent graph build, computed ONCE (was recomputed in all
// 1024 gat blocks). 4 blocks, one per i-quarter; arithmetic bitwise-identical
// to R14's per-quarter P0-P3 (same dot order, same row-sum order, same
// count/dyn/log formulas). Writes Mlg[64][66] (cols 64/65 zeroed) to ws.
__global__ __launch_bounds__(256) void mlg_kernel(
    const float* __restrict__ node_embed, const int* __restrict__ edges,
    float* __restrict__ mlgw)
{
  __shared__ float nes[1024];
  __shared__ float A[16 * 66];
  __shared__ float cnt[16 * 66];
  __shared__ float rs[16];
  const int i0 = blockIdx.x * 16;
  const int tid = threadIdx.x;
  for (int i = tid; i < 1024; i += 256) nes[i] = node_embed[i];
  for (int i = tid; i < 1056; i += 256) cnt[i] = 0.f;
  const int e0 = edges[tid], e1 = edges[256 + tid];
  __syncthreads();
  for (int idx = tid; idx < 1024; idx += 256) {
    int ir = idx >> 6, j = idx & 63;
    const float* ni = nes + (i0 + ir) * 16;
    const float* nj = nes + j * 16;
    float a = 0.f;
#pragma unroll
    for (int f = 0; f < 16; ++f) a += ni[f] * nj[f];
    A[ir * 66 + j] = a > 0.f ? a : 0.f;
  }
  if (e0 >= i0 && e0 < i0 + 16) atomicAdd(&cnt[(e0 - i0) * 66 + e1], 1.f);
  __syncthreads();
  if (tid < 16) {
    float s = 0.f;
    for (int j = 0; j < 64; ++j) s += A[tid * 66 + j];
    rs[tid] = s + 1e-6f;
  }
  __syncthreads();
  for (int idx = tid; idx < 1024; idx += 256) {
    int ir = idx >> 6, j = idx & 63;
    float dyn = (A[ir * 66 + j] / rs[ir] > 0.1f) ? 1.f : 0.f;
    float M = (i0 + ir == j) ? 1.f : (cnt[ir * 66 + j] + dyn);
    mlgw[(i0 + ir) * 66 + j] = (M > 0.f) ? __logf(M) : -INFINITY;
  }
  if (tid < 32) {                        // zero the 2-col pitch padding
    int ir = tid >> 1;
    mlgw[(i0 + ir) * 66 + 64 + (tid & 1)] = 0.f;
  }
}

// ---------------------------------------------------------------------------
// GAT layer — R14 geometry (passed @271): grid Bn*4 (i-quarters of 16 rows),
// 512 threads, one head per lane in P6, 3-step CMB combine. R16 change:
// P0-P3 graph build replaced by a 1056-float Mlg load from ws (built once by
// mlg_kernel). Layer 2's SE gate runs as 3 tiny serial phases.
// NOTE (R15 lesson): hipLaunchCooperativeKernel fails under the harness's
// stream capture — grid-wide sync is NOT available; keep kernels separate.
template <int FIN, int LAYER>
__global__ __launch_bounds__(512) void gat_kernel(
    const float* __restrict__ Xa,
    const float* __restrict__ mlgw,
    const float* __restrict__ se_w1, const float* __restrict__ se_w2,
    const float* __restrict__ gsum_in,
    const float* __restrict__ W, const float* __restrict__ a_src,
    const float* __restrict__ a_dst, const float* __restrict__ bias,
    const float* __restrict__ bnp, const float* __restrict__ skip_w,
    float* __restrict__ out, float* __restrict__ gsum_out)
{
  constexpr int XLS = 0;                 // 8448: xl, pitch 132
  constexpr int AL  = 8448;              // 4 heads x 16 x 66 = 4224 (alw)
  constexpr int MLG = AL + 4224;         // 16 x 66 = 1056 (loaded from ws)
  constexpr int XS  = MLG + 1056;        // 64*FIN
  constexpr int SS  = XS + 64 * FIN;     // 4 x 64
  constexpr int DS  = SS + 256;          // 16 x 4
  constexpr int CMB = DS + 64;           // 256 x 4
  constexpr int SEA = CMB + 1024;        // 32
  constexpr int GT  = SEA + 32;          // 32
  constexpr int R8  = GT + 32;           // 8
  constexpr int TOT = R8 + 8;
  __shared__ float sm[TOT];

  const int b  = blockIdx.x >> 2;
  const int i0 = (blockIdx.x & 3) * 16;
  const int tid = threadIdx.x;
  const int th = tid >> 8;               // 256-thread half
  const int tl = tid & 255;

  // ---- P0: zero + loads (Mlg from ws; no graph build) ----
  if (tid < 32) sm[SEA + tid] = 0.f;
  if (LAYER == 2 && tid >= 32 && tid < 64)
    sm[GT + tid - 32] = gsum_in[tid - 32] * (1.f / 8192.f);
  for (int i = tid; i < 1056; i += 512) sm[MLG + i] = mlgw[i0 * 66 + i];
  for (int i = tid; i < 64 * FIN; i += 512) sm[XS + i] = Xa[b * 64 * FIN + i];
  __syncthreads();

  // ---- SE gate (layer 2 only): 3 tiny phases, then gate Xs ----
  if (LAYER == 2) {
    if (tid < 8) {
      float a = 0.f;
      for (int f = 0; f < 32; ++f) a += sm[GT + f] * se_w1[tid * 32 + f];
      sm[R8 + tid] = fmaxf(a, 0.f);
    }
    __syncthreads();
    if (tid < 32) {
      float a = 0.f;
      for (int k = 0; k < 8; ++k) a += sm[R8 + k] * se_w2[tid * 8 + k];
      sm[GT + tid] = 1.f / (1.f + __expf(-a));
    }
    __syncthreads();
    for (int i = tid; i < 64 * FIN; i += 512) sm[XS + i] *= sm[GT + (i & 31)];
    __syncthreads();
  }

  // ---- P4: xl = X W (pitch 132), full 64 rows ----
  {
    const int fo = tid & 127, q4r = tid >> 7;
    float wcol[FIN];
#pragma unroll
    for (int q = 0; q < FIN; ++q) wcol[q] = W[q * 128 + fo];
    for (int nn = q4r; nn < 64; nn += 4) {
      float acc = 0.f;
#pragma unroll
      for (int q = 0; q < FIN; ++q) acc += sm[XS + nn * FIN + q] * wcol[q];
      sm[XLS + nn * 132 + fo] = acc;
    }
  }
  __syncthreads();

  // ---- P5: attention terms: s for all j, d for the i-quarter ----
  if (tid < 256) {
    const int nn = tid >> 2, h = tid & 3;
    float s = 0.f;
    for (int q = 0; q < 32; ++q)
      s += sm[XLS + nn * 132 + h * 32 + q] * a_src[h * 32 + q];
    sm[SS + h * 64 + nn] = s;
  } else if (tid < 320) {
    const int idx = tid - 256, ir = idx >> 2, h = idx & 3;
    float d = 0.f;
    for (int q = 0; q < 32; ++q)
      d += sm[XLS + (i0 + ir) * 132 + h * 32 + q] * a_dst[h * 32 + q];
    sm[DS + ir * 4 + h] = d;
  }
  __syncthreads();

  // ---- P6: ONE head per lane: h = (tl>>7)*2 + th; 8 lanes/row softmax ----
  const int hsel = tl >> 7;
  const int ir   = (tl >> 3) & 15;
  const int q4   = tl & 7;
  const int h    = hsel * 2 + th;
  float* alw = sm + AL + h * 1056;
  float accT[4];
  {
    const float dterm = sm[DS + ir * 4 + h];
    float lg[8];
    float mx = -INFINITY;
#pragma unroll
    for (int k = 0; k < 8; ++k) {
      int j = q4 * 8 + k;
      float e = dterm + sm[SS + h * 64 + j];
      e = e >= 0.f ? e : 0.2f * e;
      float v = e + sm[MLG + ir * 66 + j];
      lg[k] = v;
      mx = fmaxf(mx, v);
    }
    mx = fmaxf(mx, __shfl_xor(mx, 1, 8));
    mx = fmaxf(mx, __shfl_xor(mx, 2, 8));
    mx = fmaxf(mx, __shfl_xor(mx, 4, 8));
    float sum = 0.f;
#pragma unroll
    for (int k = 0; k < 8; ++k) { lg[k] = __expf(lg[k] - mx); sum += lg[k]; }
    sum += __shfl_xor(sum, 1, 8);
    sum += __shfl_xor(sum, 2, 8);
    sum += __shfl_xor(sum, 4, 8);
    const float inv = 1.f / sum;
#pragma unroll
    for (int k = 0; k < 8; ++k) alw[ir * 66 + q4 * 8 + k] = lg[k];
    // readers are the same 8 lanes (lockstep wave) -> no barrier needed
    float a0 = 0.f, a1 = 0.f, a2 = 0.f, a3 = 0.f;
#pragma unroll 8
    for (int j = 0; j < 64; ++j) {
      float av = alw[ir * 66 + j];
      float4 xv = *(const float4*)&sm[XLS + j * 132 + h * 32 + q4 * 4];
      a0 += av * xv.x; a1 += av * xv.y; a2 += av * xv.z; a3 += av * xv.w;
    }
    accT[0] = a0 * inv; accT[1] = a1 * inv;
    accT[2] = a2 * inv; accT[3] = a3 * inv;
  }

  // ---- P7: 3-step head combine via CMB, epilogue on (th0, hsel0) ----
  if (th == 1) *(float4*)&sm[CMB + tl * 4] = make_float4(accT[0], accT[1], accT[2], accT[3]);
  __syncthreads();
  if (th == 0 && hsel == 1) {
    const float4 o = *(const float4*)&sm[CMB + tl * 4];
    accT[0] += o.x; accT[1] += o.y; accT[2] += o.z; accT[3] += o.w;
    *(float4*)&sm[CMB + tl * 4] = make_float4(accT[0], accT[1], accT[2], accT[3]);
  }
  __syncthreads();
  if (th == 0 && hsel == 0) {
    const float4 o1  = *(const float4*)&sm[CMB + tl * 4];
    const float4 o23 = *(const float4*)&sm[CMB + (tl + 128) * 4];
    accT[0] += o1.x + o23.x; accT[1] += o1.y + o23.y;
    accT[2] += o1.z + o23.z; accT[3] += o1.w + o23.w;
    const int i = i0 + ir;
    float res[4];
#pragma unroll
    for (int r = 0; r < 4; ++r) {
      int f = q4 * 4 + r;
      float bsc = bnp[f] * rsqrtf(bnp[96 + f] + 1e-5f);
      float bsh = bnp[32 + f] - bnp[64 + f] * bsc;
      float v = accT[r] * 0.25f + bias[f];
      v = v * bsc + bsh;
      float skip;
      if (LAYER == 1) {
        skip = 0.f;
#pragma unroll
        for (int q = 0; q < 16; ++q) skip += sm[XS + i * 16 + q] * skip_w[f * 16 + q];
      } else {
        skip = sm[XS + i * 32 + f];
      }
      v += skip;
      v = 0.5f * v * (1.f + erff(v * 0.70710678118654752440f));
      res[r] = v;
      atomicAdd(&sm[SEA + f], v);
    }
    *(float4*)&out[(b * 64 + i) * 32 + q4 * 4] = make_float4(res[0], res[1], res[2], res[3]);
  }
  __syncthreads();
  if (tid < 32) atomicAdd(&gsum_out[tid], sm[SEA + tid]);
}

// ---------------------------------------------------------------------------
// SE2 gate (redundant per block) + pool over C + classifier.
__global__ __launch_bounds__(64) void out_kernel(
    const float* __restrict__ tmp2, const float* __restrict__ gsum2,
    const float* __restrict__ se_w1, const float* __restrict__ se_w2,
    const float* __restrict__ clf_w, const float* __restrict__ clf_b,
    float* __restrict__ outp)
{
  __shared__ float mean32[32], r8[8], gate[32], pl[32];
  const int b = blockIdx.x, tid = threadIdx.x;
  if (tid < 32) mean32[tid] = gsum2[tid] * (1.f / 8192.f);
  __syncthreads();
  if (tid < 8) {
    float a = 0.f;
    for (int f = 0; f < 32; ++f) a += mean32[f] * se_w1[tid * 32 + f];
    r8[tid] = a > 0.f ? a : 0.f;
  }
  __syncthreads();
  if (tid < 32) {
    float a = 0.f;
    for (int k = 0; k < 8; ++k) a += r8[k] * se_w2[tid * 8 + k];
    gate[tid] = 1.f / (1.f + __expf(-a));
  }
  __syncthreads();
  if (tid < 32) {
    float a = 0.f;
    for (int n = 0; n < 64; ++n) a += tmp2[(b * 64 + n) * 32 + tid];
    pl[tid] = a * (1.f / 64.f) * gate[tid];
  }
  __syncthreads();
  if (tid < 2) {
    float a = clf_b[tid];
    for (int f = 0; f < 32; ++f) a += pl[f] * clf_w[tid * 32 + f];
    outp[b * 2 + tid] = a;
  }
}

// ---------------------------------------------------------------------------
extern "C" void kernel_launch(void* const* d_in, const int* in_sizes, int n_in,
                              void* d_out, int out_size, void* d_ws, size_t ws_size,
                              hipStream_t stream)
{
  const float* x          = (const float*)d_in[0];
  const int*   edges      = (const int*)d_in[1];
  const float* conv1_w    = (const float*)d_in[2];
  const float* bn_c1      = (const float*)d_in[3];
  const float* dw_w       = (const float*)d_in[4];
  const float* bn_c2      = (const float*)d_in[5];
  const float* sdw_w      = (const float*)d_in[6];
  const float* spw_w      = (const float*)d_in[7];
  const float* bn_c3      = (const float*)d_in[8];
  const float* node_embed = (const float*)d_in[9];
  const float* gat1_w     = (const float*)d_in[10];
  const float* gat1_asrc  = (const float*)d_in[11];
  const float* gat1_adst  = (const float*)d_in[12];
  const float* gat1_bias  = (const float*)d_in[13];
  const float* bn_g1      = (const float*)d_in[14];
  const float* skip1_w    = (const float*)d_in[15];
  const float* se1_w1     = (const float*)d_in[16];
  const float* se1_w2     = (const float*)d_in[17];
  const float* gat2_w     = (const float*)d_in[18];
  const float* gat2_asrc  = (const float*)d_in[19];
  const float* gat2_adst  = (const float*)d_in[20];
  const float* gat2_bias  = (const float*)d_in[21];
  const float* bn_g2      = (const float*)d_in[22];
  const float* se2_w1     = (const float*)d_in[23];
  const float* se2_w2     = (const float*)d_in[24];
  const float* clf_w      = (const float*)d_in[25];
  const float* clf_b      = (const float*)d_in[26];

  float* ws    = (float*)d_ws;
  float* feats = ws;             // 131072 floats  [B*C, 16]
  float* tmp1  = ws + 131072;    // 262144         [B*C, 32]
  float* tmp2  = ws + 393216;    // 262144         [B*C, 32]
  float* gs    = ws + 655360;    // 64: gsum1[32] | gsum2[32]
  float* mlgw  = ws + 655424;    // 4224: Mlg[64][66]

  mlg_kernel<<<4, 256, 0, stream>>>(node_embed, edges, mlgw);
  feat_kernel<<<Bn * Cn, 256, 0, stream>>>(x, conv1_w, bn_c1, dw_w, bn_c2,
                                           sdw_w, spw_w, bn_c3, feats, gs);
  gat_kernel<16, 1><<<Bn * 4, 512, 0, stream>>>(
      feats, mlgw, nullptr, nullptr, nullptr,
      gat1_w, gat1_asrc, gat1_adst, gat1_bias, bn_g1, skip1_w, tmp1, gs);
  gat_kernel<32, 2><<<Bn * 4, 512, 0, stream>>>(
      tmp1, mlgw, se1_w1, se1_w2, gs,
      gat2_w, gat2_asrc, gat2_adst, gat2_bias, bn_g2, nullptr, tmp2, gs + 32);
  out_kernel<<<Bn, 64, 0, stream>>>(tmp2, gs + 32, se2_w1, se2_w2, clf_w, clf_b,
                                    (float*)d_out);
}